// Round 1
// 4811.891 us; speedup vs baseline: 1.9043x; 1.9043x over previous
//
#include <hip/hip_runtime.h>
#include <hip/hip_bf16.h>
#include <math.h>

// GPT-2 small forward: B=2, S=1024, V=50257, E=768, H=12, L=4, D=64
// GEMMs: split-bf16 (hi+lo) MFMA, ~fp32 accuracy at matrix-core rate.

#define Bb 2
#define Ss 1024
#define Vv 50257
#define Ee 768
#define Hh 12
#define Ll 4
#define Dd 64
#define E3 2304   // 3*E
#define E4 3072   // 4*E
#define ROWS 2048 // B*S

typedef __attribute__((ext_vector_type(8))) short bf16x8;  // 8 bf16 = 4 VGPRs
typedef __attribute__((ext_vector_type(4))) float f32x4;

static __device__ __forceinline__ unsigned short bfbits(__hip_bfloat16 h) {
    unsigned short u;
    __builtin_memcpy(&u, &h, 2);
    return u;
}

// Split two fp32 into packed hi (2xbf16 in u32) and packed lo.
// hi = bf16_rne(f); lo = bf16_rne(f - hi). hi+lo carries ~17 mantissa bits.
static __device__ __forceinline__ void split2(float f0, float f1,
                                              unsigned int& hi, unsigned int& lo) {
    __hip_bfloat16 h0 = __float2bfloat16(f0);
    __hip_bfloat16 h1 = __float2bfloat16(f1);
    float r0 = f0 - __bfloat162float(h0);
    float r1 = f1 - __bfloat162float(h1);
    __hip_bfloat16 g0 = __float2bfloat16(r0);
    __hip_bfloat16 g1 = __float2bfloat16(r1);
    hi = (unsigned int)bfbits(h0) | ((unsigned int)bfbits(h1) << 16);
    lo = (unsigned int)bfbits(g0) | ((unsigned int)bfbits(g1) << 16);
}

// ---------------------------------------------------------------------------
// Embedding: x[row] = wte[ids[row]] + wpe[row % S]
// ---------------------------------------------------------------------------
__global__ __launch_bounds__(256) void embed_kernel(
    const int* __restrict__ ids, const float* __restrict__ wte,
    const float* __restrict__ wpe, float* __restrict__ x)
{
    int row = blockIdx.x;
    int s = row & (Ss - 1);
    int id = ids[row];
    const float* wt = wte + (size_t)id * Ee;
    const float* wp = wpe + (size_t)s * Ee;
    float* xr = x + (size_t)row * Ee;
    for (int i = 0; i < 3; ++i) {
        int c = threadIdx.x + i * 256;
        xr[c] = wt[c] + wp[c];
    }
}

// ---------------------------------------------------------------------------
// LayerNorm: one block (256 thr) per row of 768
// ---------------------------------------------------------------------------
__global__ __launch_bounds__(256) void ln_kernel(
    const float* __restrict__ x, const float* __restrict__ gain,
    const float* __restrict__ bias, float* __restrict__ out)
{
    int row = blockIdx.x;
    int tid = threadIdx.x;
    const float* xr = x + (size_t)row * Ee;
    float v0 = xr[tid], v1 = xr[tid + 256], v2 = xr[tid + 512];

    __shared__ float red1[4];
    __shared__ float red2[4];

    float sum = v0 + v1 + v2;
    #pragma unroll
    for (int o = 32; o > 0; o >>= 1) sum += __shfl_down(sum, o, 64);
    if ((tid & 63) == 0) red1[tid >> 6] = sum;
    __syncthreads();
    float mu = (red1[0] + red1[1] + red1[2] + red1[3]) * (1.0f / 768.0f);

    float d0 = v0 - mu, d1 = v1 - mu, d2 = v2 - mu;
    float vs = d0 * d0 + d1 * d1 + d2 * d2;
    #pragma unroll
    for (int o = 32; o > 0; o >>= 1) vs += __shfl_down(vs, o, 64);
    if ((tid & 63) == 0) red2[tid >> 6] = vs;
    __syncthreads();
    float var = (red2[0] + red2[1] + red2[2] + red2[3]) * (1.0f / 768.0f);
    float rs = rsqrtf(var + 1e-6f);

    float* orow = out + (size_t)row * Ee;
    orow[tid]       = d0 * rs * gain[tid]       + bias[tid];
    orow[tid + 256] = d1 * rs * gain[tid + 256] + bias[tid + 256];
    orow[tid + 512] = d2 * rs * gain[tid + 512] + bias[tid + 512];
}

// ---------------------------------------------------------------------------
// GELU (tanh approximation, flax default)
// ---------------------------------------------------------------------------
__device__ __forceinline__ float gelu_f(float x) {
    const float k = 0.7978845608028654f; // sqrt(2/pi)
    float x3 = x * x * x;
    return 0.5f * x * (1.0f + tanhf(k * (x + 0.044715f * x3)));
}

// ---------------------------------------------------------------------------
// Split-bf16 MFMA GEMM: C[M,N] = act(A[M,K] @ W[K,N] + bias) (+ R)
// 128x128 tile, BK=32, 256 threads (4 waves), each wave owns a 64x64 subtile
// as 4x4 fragments of 16x16. Per k-step, per fragment: 3 MFMAs
// (hi*hi + hi*lo + lo*hi) -> ~fp32 accuracy.
//
// LDS layout is chunk-major: tile[k_octet][row][8 bf16]. Both the transpose
// staging writes (consecutive n -> consecutive 16B) and the fragment reads
// (consecutive rows -> consecutive 16B) are bank-conflict-free b128 ops.
// A and W fragments use the same (lane-group, elem)->k assignment, so the
// MFMA k-permutation cancels regardless of the HW's internal mapping.
// ---------------------------------------------------------------------------
template <int ACT, int RES>
__global__ __launch_bounds__(256) void gemm_mfma_kernel(
    const float* __restrict__ A, const float* __restrict__ W,
    const float* __restrict__ bias, const float* __restrict__ R,
    float* __restrict__ C, int M, int N, int K)
{
    __shared__ unsigned short Ah[4][128][8];
    __shared__ unsigned short Al[4][128][8];
    __shared__ unsigned short Wh[4][128][8];
    __shared__ unsigned short Wl[4][128][8];

    int tid = (int)threadIdx.x;

    // XCD-aware swizzle of the flat block id (all grids here are %8 == 0).
    int gx = (int)gridDim.x;
    int nwg = gx * (int)gridDim.y;
    int flat = (int)blockIdx.y * gx + (int)blockIdx.x;
    if ((nwg & 7) == 0) flat = (flat & 7) * (nwg >> 3) + (flat >> 3);
    int bx = flat % gx, by = flat / gx;
    int m0 = by * 128, n0 = bx * 128;

    int lane = tid & 63;
    int wid  = tid >> 6;
    int wr = wid >> 1, wc = wid & 1;   // wave subtile (2x2 of 64x64)
    int lr = lane & 15, lg = lane >> 4;

    // staging assignment
    int arow = tid >> 1;            // 0..127 : A tile row
    int as0  = (tid & 1) * 2;       // A k-octet base {0,2}
    int wn   = tid & 127;           // 0..127 : W tile col (n)
    int ws0  = (tid >> 7) * 2;      // W k-octet base {0,2}

    const float* Arow = A + (size_t)(m0 + arow) * K + as0 * 8;
    const float* Wcol = W + (size_t)(ws0 * 8) * N + (n0 + wn);
    bool wvalid = (n0 + wn) < N;    // only LM head has ragged N

    f32x4 acc[4][4];
    #pragma unroll
    for (int i = 0; i < 4; ++i)
        #pragma unroll
        for (int j = 0; j < 4; ++j)
            acc[i][j] = (f32x4){0.f, 0.f, 0.f, 0.f};

    for (int kb = 0; kb < K; kb += 32) {
        // ---- global loads (registers only, before barrier) ----
        float4 av0 = *(const float4*)(Arow + kb);
        float4 av1 = *(const float4*)(Arow + kb + 4);
        float4 av2 = *(const float4*)(Arow + kb + 8);
        float4 av3 = *(const float4*)(Arow + kb + 12);
        float wv[16];
        const float* wp = Wcol + (size_t)kb * N;
        #pragma unroll
        for (int j = 0; j < 16; ++j)
            wv[j] = wvalid ? wp[(size_t)j * N] : 0.0f;

        // ---- convert to split bf16 ----
        unsigned int ahw[8], alw[8], whw[8], wlw[8];
        split2(av0.x, av0.y, ahw[0], alw[0]);
        split2(av0.z, av0.w, ahw[1], alw[1]);
        split2(av1.x, av1.y, ahw[2], alw[2]);
        split2(av1.z, av1.w, ahw[3], alw[3]);
        split2(av2.x, av2.y, ahw[4], alw[4]);
        split2(av2.z, av2.w, ahw[5], alw[5]);
        split2(av3.x, av3.y, ahw[6], alw[6]);
        split2(av3.z, av3.w, ahw[7], alw[7]);
        #pragma unroll
        for (int j = 0; j < 8; ++j)
            split2(wv[2 * j], wv[2 * j + 1], whw[j], wlw[j]);

        __syncthreads();  // previous iteration's fragment reads complete

        *(uint4*)(&Ah[as0    ][arow][0]) = make_uint4(ahw[0], ahw[1], ahw[2], ahw[3]);
        *(uint4*)(&Ah[as0 + 1][arow][0]) = make_uint4(ahw[4], ahw[5], ahw[6], ahw[7]);
        *(uint4*)(&Al[as0    ][arow][0]) = make_uint4(alw[0], alw[1], alw[2], alw[3]);
        *(uint4*)(&Al[as0 + 1][arow][0]) = make_uint4(alw[4], alw[5], alw[6], alw[7]);
        *(uint4*)(&Wh[ws0    ][wn][0])   = make_uint4(whw[0], whw[1], whw[2], whw[3]);
        *(uint4*)(&Wh[ws0 + 1][wn][0])   = make_uint4(whw[4], whw[5], whw[6], whw[7]);
        *(uint4*)(&Wl[ws0    ][wn][0])   = make_uint4(wlw[0], wlw[1], wlw[2], wlw[3]);
        *(uint4*)(&Wl[ws0 + 1][wn][0])   = make_uint4(wlw[4], wlw[5], wlw[6], wlw[7]);

        __syncthreads();  // staging visible

        // ---- fragments + MFMA ----
        bf16x8 afh[4], afl[4], wfh[4], wfl[4];
        #pragma unroll
        for (int mi = 0; mi < 4; ++mi) {
            int r = wr * 64 + mi * 16 + lr;
            afh[mi] = *(const bf16x8*)(&Ah[lg][r][0]);
            afl[mi] = *(const bf16x8*)(&Al[lg][r][0]);
        }
        #pragma unroll
        for (int nj = 0; nj < 4; ++nj) {
            int n = wc * 64 + nj * 16 + lr;
            wfh[nj] = *(const bf16x8*)(&Wh[lg][n][0]);
            wfl[nj] = *(const bf16x8*)(&Wl[lg][n][0]);
        }
        #pragma unroll
        for (int mi = 0; mi < 4; ++mi)
            #pragma unroll
            for (int nj = 0; nj < 4; ++nj) {
                f32x4 c = acc[mi][nj];
                c = __builtin_amdgcn_mfma_f32_16x16x32_bf16(afh[mi], wfl[nj], c, 0, 0, 0);
                c = __builtin_amdgcn_mfma_f32_16x16x32_bf16(afl[mi], wfh[nj], c, 0, 0, 0);
                c = __builtin_amdgcn_mfma_f32_16x16x32_bf16(afh[mi], wfh[nj], c, 0, 0, 0);
                acc[mi][nj] = c;
            }
    }

    // ---- epilogue: D col = lane&15, row = (lane>>4)*4 + reg ----
    #pragma unroll
    for (int mi = 0; mi < 4; ++mi) {
        int gm0 = m0 + wr * 64 + mi * 16 + lg * 4;
        #pragma unroll
        for (int nj = 0; nj < 4; ++nj) {
            int gn = n0 + wc * 64 + nj * 16 + lr;
            if (gn < N) {
                float bv = bias ? bias[gn] : 0.0f;
                #pragma unroll
                for (int rg = 0; rg < 4; ++rg) {
                    float v = acc[mi][nj][rg] + bv;
                    if (ACT == 1) v = gelu_f(v);
                    if (RES) v += R[(size_t)(gm0 + rg) * N + gn];
                    C[(size_t)(gm0 + rg) * N + gn] = v;
                }
            }
        }
    }
}

// ---------------------------------------------------------------------------
// Flash-style causal attention, fp32, 64x64 tiles. (unchanged this round)
// grid (qtile=16, head=12, batch=2), block 256.
// ---------------------------------------------------------------------------
__global__ __launch_bounds__(256) void attn_kernel(
    const float* __restrict__ qkv, float* __restrict__ out)
{
    int qt = blockIdx.x, h = blockIdx.y, b = blockIdx.z;
    __shared__ float Qs[64][65];
    __shared__ float Ks[64][65];
    __shared__ float Vs[64][65];
    __shared__ float Ps[64][65];

    int tid = threadIdx.x;
    int base_row = b * Ss;
    int colq = h * Dd;

    for (int i = 0; i < 16; ++i) {
        int idx = tid + i * 256;
        int r = idx >> 6, d = idx & 63;
        Qs[r][d] = qkv[(size_t)(base_row + qt * 64 + r) * E3 + colq + d];
    }

    int r = tid >> 2;
    int dq = (tid & 3) * 16;
    int qrow_g = qt * 64 + r;

    float O[16];
    #pragma unroll
    for (int i = 0; i < 16; ++i) O[i] = 0.0f;
    float mrow = -1e30f, lrow = 0.0f;

    for (int kt = 0; kt <= qt; ++kt) {
        __syncthreads();
        for (int i = 0; i < 16; ++i) {
            int idx = tid + i * 256;
            int rr = idx >> 6, d = idx & 63;
            size_t off = (size_t)(base_row + kt * 64 + rr) * E3 + colq;
            Ks[rr][d] = qkv[off + 768 + d];
            Vs[rr][d] = qkv[off + 1536 + d];
        }
        __syncthreads();

        for (int j = 0; j < 16; ++j) {
            int kc = dq + j;
            float sacc = 0.0f;
            #pragma unroll 8
            for (int d = 0; d < 64; ++d) sacc = fmaf(Qs[r][d], Ks[kc][d], sacc);
            sacc *= 0.125f;
            if (kt == qt && (kt * 64 + kc) > qrow_g) sacc = -10000.0f;
            Ps[r][kc] = sacc;
        }
        __syncthreads();

        float tmax = -1e30f;
        for (int j = 0; j < 64; ++j) tmax = fmaxf(tmax, Ps[r][j]);
        float mnew = fmaxf(mrow, tmax);
        float alpha = __expf(mrow - mnew);
        #pragma unroll
        for (int i = 0; i < 16; ++i) O[i] *= alpha;
        float psum = 0.0f;
        for (int j = 0; j < 64; ++j) {
            float p = __expf(Ps[r][j] - mnew);
            psum += p;
            #pragma unroll
            for (int i = 0; i < 16; ++i) O[i] = fmaf(p, Vs[j][dq + i], O[i]);
        }
        lrow = lrow * alpha + psum;
        mrow = mnew;
    }

    float inv = 1.0f / lrow;
    float* orow = out + (size_t)(base_row + qt * 64 + r) * Ee + colq + dq;
    #pragma unroll
    for (int i = 0; i < 16; ++i) orow[i] = O[i] * inv;
}

// ---------------------------------------------------------------------------
// Host orchestration
// ---------------------------------------------------------------------------
extern "C" void kernel_launch(void* const* d_in, const int* in_sizes, int n_in,
                              void* d_out, int out_size, void* d_ws, size_t ws_size,
                              hipStream_t stream)
{
    const int*   ids   = (const int*)  d_in[0];
    const float* wte   = (const float*)d_in[1];
    const float* wpe   = (const float*)d_in[2];
    const float* ln1_s = (const float*)d_in[3];
    const float* ln1_b = (const float*)d_in[4];
    const float* w_qkv = (const float*)d_in[5];
    const float* b_qkv = (const float*)d_in[6];
    const float* w_ao  = (const float*)d_in[7];
    const float* b_ao  = (const float*)d_in[8];
    const float* ln2_s = (const float*)d_in[9];
    const float* ln2_b = (const float*)d_in[10];
    const float* w_fc  = (const float*)d_in[11];
    const float* b_fc  = (const float*)d_in[12];
    const float* w_mp  = (const float*)d_in[13];
    const float* b_mp  = (const float*)d_in[14];
    const float* lnf_s = (const float*)d_in[15];
    const float* lnf_b = (const float*)d_in[16];
    const float* w_lm  = (const float*)d_in[17];
    float* out = (float*)d_out;

    // workspace layout (floats): x, h, qkv, attno, hfc  -> 15.73M floats (62.9 MB)
    float* ws    = (float*)d_ws;
    float* x     = ws;
    float* hbuf  = x     + (size_t)ROWS * Ee;
    float* qkvb  = hbuf  + (size_t)ROWS * Ee;
    float* attno = qkvb  + (size_t)ROWS * E3;
    float* hfc   = attno + (size_t)ROWS * Ee;

    embed_kernel<<<ROWS, 256, 0, stream>>>(ids, wte, wpe, x);

    for (int l = 0; l < Ll; ++l) {
        // LN1
        ln_kernel<<<ROWS, 256, 0, stream>>>(x, ln1_s + l * Ee, ln1_b + l * Ee, hbuf);
        // qkv = h @ w_qkv + b_qkv   [2048, 2304]
        gemm_mfma_kernel<0, 0><<<dim3(E3 / 128, ROWS / 128), 256, 0, stream>>>(
            hbuf, w_qkv + (size_t)l * Ee * E3, b_qkv + (size_t)l * E3, nullptr,
            qkvb, ROWS, E3, Ee);
        // attention
        attn_kernel<<<dim3(16, Hh, Bb), 256, 0, stream>>>(qkvb, attno);
        // x = x + attno @ w_ao + b_ao
        gemm_mfma_kernel<0, 1><<<dim3(Ee / 128, ROWS / 128), 256, 0, stream>>>(
            attno, w_ao + (size_t)l * Ee * Ee, b_ao + (size_t)l * Ee, x,
            x, ROWS, Ee, Ee);
        // LN2
        ln_kernel<<<ROWS, 256, 0, stream>>>(x, ln2_s + l * Ee, ln2_b + l * Ee, hbuf);
        // hfc = gelu(h @ w_fc + b_fc)   [2048, 3072]
        gemm_mfma_kernel<1, 0><<<dim3(E4 / 128, ROWS / 128), 256, 0, stream>>>(
            hbuf, w_fc + (size_t)l * Ee * E4, b_fc + (size_t)l * E4, nullptr,
            hfc, ROWS, E4, Ee);
        // x = x + hfc @ w_mp + b_mp
        gemm_mfma_kernel<0, 1><<<dim3(Ee / 128, ROWS / 128), 256, 0, stream>>>(
            hfc, w_mp + (size_t)l * E4 * Ee, b_mp + (size_t)l * Ee, x,
            x, ROWS, Ee, E4);
    }

    // final LN
    ln_kernel<<<ROWS, 256, 0, stream>>>(x, lnf_s, lnf_b, hbuf);
    // logits = h @ w_lm   [2048, 50257]  (393 n-tiles: 50304 padded, guarded)
    gemm_mfma_kernel<0, 0><<<dim3((Vv + 127) / 128, ROWS / 128), 256, 0, stream>>>(
        hbuf, w_lm, nullptr, nullptr, out, ROWS, Vv, Ee);
}